// Round 5
// baseline (476.151 us; speedup 1.0000x reference)
//
#include <hip/hip_runtime.h>

#define FEATSIZE 4096
#define TPB 256

typedef float f32x4 __attribute__((ext_vector_type(4)));

// One block per row. Radix-select (MSB-first, 8 bits x 4 passes) over
// order-preserving u32 keys held entirely in registers (16/thread).
// Pass-1 histogram interleaved under the global loads; passes 2-4 iterate a
// per-thread candidate bitmask (~16 survivors/block) instead of 16 predicated
// atomics; equality-rank via ballot+popc; double-buffered hist -> 3 barriers/pass.
__global__ __launch_bounds__(TPB, 4) void adaptive_drop_kernel(
    const float* __restrict__ feat,
    const float* __restrict__ prop,
    const float* __restrict__ scale,
    float* __restrict__ out)
{
    __shared__ unsigned int hist[2][256];
    __shared__ unsigned int wtot[4];
    __shared__ unsigned int wsum[16];
    __shared__ unsigned int selB;
    __shared__ unsigned int selE;

    const int row  = blockIdx.x;
    const int t    = threadIdx.x;
    const int lane = t & 63;
    const int w    = t >> 6;

    const float p      = prop[row];
    const float rscale = scale[0] / p;
    int k = (int)rintf((float)FEATSIZE * p);   // matches jnp.round (half-to-even)
    k = k < 0 ? 0 : (k > FEATSIZE ? FEATSIZE : k);

    const f32x4* frow = reinterpret_cast<const f32x4*>(feat + (size_t)row * FEATSIZE);
    f32x4*       orow = reinterpret_cast<f32x4*>(out + (size_t)row * FEATSIZE);

    hist[0][t] = 0;
    hist[1][t] = 0;
    __syncthreads();

    // ---- loads issued together; pass-1 atomics per chunk hide under vmcnt ----
    f32x4 v0 = __builtin_nontemporal_load(&frow[0 * TPB + t]);
    f32x4 v1 = __builtin_nontemporal_load(&frow[1 * TPB + t]);
    f32x4 v2 = __builtin_nontemporal_load(&frow[2 * TPB + t]);
    f32x4 v3 = __builtin_nontemporal_load(&frow[3 * TPB + t]);

    unsigned int keys[16];
#define PROC_CHUNK(J, V)                                                        \
    do {                                                                        \
        _Pragma("unroll")                                                       \
        for (int c = 0; c < 4; ++c) {                                           \
            unsigned int u_ = __float_as_uint((V)[c]);                          \
            unsigned int key_ =                                                 \
                u_ ^ ((u_ & 0x80000000u) ? 0xFFFFFFFFu : 0x80000000u);          \
            keys[(J) * 4 + c] = key_;                                           \
            atomicAdd(&hist[0][key_ >> 24], 1u);                                \
        }                                                                       \
    } while (0)
    PROC_CHUNK(0, v0);
    PROC_CHUNK(1, v1);
    PROC_CHUNK(2, v2);
    PROC_CHUNK(3, v3);
#undef PROC_CHUNK

    // ---- trivial cases (block-uniform; not hit with setup's prop range) ----
    if (k <= 0 || k >= FEATSIZE) {
        const float m = (k >= FEATSIZE) ? rscale : 0.0f;
#pragma unroll
        for (int j = 0; j < 4; ++j) {
            f32x4 o;
#pragma unroll
            for (int c = 0; c < 4; ++c) {
                unsigned int key = keys[j * 4 + c];
                unsigned int u = (key & 0x80000000u) ? (key ^ 0x80000000u) : ~key;
                o[c] = __uint_as_float(u) * m;
            }
            __builtin_nontemporal_store(o, &orow[j * TPB + t]);
        }
        return;
    }

    // ---- radix select: find key T of rank k-1 (0-indexed ascending) ----
    int s = k - 1;
    unsigned int prefix = 0;
    unsigned int cand = 0;

    // pass 1 scan (histogram already built above)
    {
        __syncthreads();
        unsigned int val  = hist[0][t];
        unsigned int incl = val;
#pragma unroll
        for (int off = 1; off < 64; off <<= 1) {
            unsigned int o = __shfl_up(incl, (unsigned)off, 64);
            if (lane >= off) incl += o;
        }
        if (lane == 63) wtot[w] = incl;
        __syncthreads();
        unsigned int base = 0;
#pragma unroll
        for (int ww = 0; ww < 3; ++ww) if (ww < w) base += wtot[ww];
        const unsigned int cumIncl = base + incl;
        const unsigned int cumExcl = cumIncl - val;
        if (val != 0u && (int)cumExcl <= s && s < (int)cumIncl) {
            selB = (unsigned int)t;   // exactly one thread matches
            selE = cumExcl;
        }
        __syncthreads();
        const unsigned int b = selB;
        s -= (int)selE;
        prefix = b << 24;
#pragma unroll
        for (int e = 0; e < 16; ++e)
            if ((keys[e] >> 24) == b) cand |= (1u << e);
    }

    // passes 2..4: only candidate elements participate (~16 in whole block)
#pragma unroll
    for (int pp = 1; pp < 4; ++pp) {
        const int shift = 24 - 8 * pp;
        unsigned int* H = hist[pp & 1];
        unsigned int m = cand;
        while (m) {
            const int e = __builtin_ctz(m);
            m &= m - 1;
            atomicAdd(&H[(keys[e] >> shift) & 255u], 1u);
        }
        hist[(pp & 1) ^ 1][t] = 0;   // re-zero the buffer the NEXT pass will use
        __syncthreads();
        unsigned int val  = H[t];
        unsigned int incl = val;
#pragma unroll
        for (int off = 1; off < 64; off <<= 1) {
            unsigned int o = __shfl_up(incl, (unsigned)off, 64);
            if (lane >= off) incl += o;
        }
        if (lane == 63) wtot[w] = incl;
        __syncthreads();
        unsigned int base = 0;
#pragma unroll
        for (int ww = 0; ww < 3; ++ww) if (ww < w) base += wtot[ww];
        const unsigned int cumIncl = base + incl;
        const unsigned int cumExcl = cumIncl - val;
        if (val != 0u && (int)cumExcl <= s && s < (int)cumIncl) {
            selB = (unsigned int)t;
            selE = cumExcl;
        }
        __syncthreads();
        const unsigned int b = selB;
        s -= (int)selE;
        prefix |= b << shift;
        unsigned int nm = 0;
        m = cand;
        while (m) {
            const int e = __builtin_ctz(m);
            m &= m - 1;
            if (((keys[e] >> shift) & 255u) == b) nm |= (1u << e);
        }
        cand = nm;
    }

    const unsigned int T = prefix;
    const int keepEq = s + 1;   // # of elements equal to T to keep (lowest index first)

    // ---- stable rank among elements equal to T via ballot+popc ----
    const unsigned long long below = (1ULL << lane) - 1ULL;
    unsigned int laneExclJ[4];
#pragma unroll
    for (int j = 0; j < 4; ++j) {
        const unsigned long long m0 = __ballot(keys[j * 4 + 0] == T);
        const unsigned long long m1 = __ballot(keys[j * 4 + 1] == T);
        const unsigned long long m2 = __ballot(keys[j * 4 + 2] == T);
        const unsigned long long m3 = __ballot(keys[j * 4 + 3] == T);
        laneExclJ[j] = (unsigned int)(__popcll(m0 & below) + __popcll(m1 & below) +
                                      __popcll(m2 & below) + __popcll(m3 & below));
        if (lane == 0)
            wsum[j * 4 + w] = (unsigned int)(__popcll(m0) + __popcll(m1) +
                                             __popcll(m2) + __popcll(m3));
    }
    __syncthreads();
    unsigned int chunkExcl[4];
    {
        unsigned int run = 0;
#pragma unroll
        for (int m = 0; m < 16; ++m) {           // m = j*4 + w, global index order
            if ((m & 3) == w) chunkExcl[m >> 2] = run;
            run += wsum[m];
        }
    }

    // ---- masked, scaled write-out (coalesced float4, nontemporal) ----
#pragma unroll
    for (int j = 0; j < 4; ++j) {
        f32x4 o;
        const unsigned int base = chunkExcl[j] + laneExclJ[j];
        unsigned int eqseen = 0;
#pragma unroll
        for (int c = 0; c < 4; ++c) {
            const unsigned int key = keys[j * 4 + c];
            const unsigned int u = (key & 0x80000000u) ? (key ^ 0x80000000u) : ~key;
            const float f = __uint_as_float(u);
            bool keep;
            if (key < T)       keep = true;
            else if (key == T) { keep = ((int)(base + eqseen) < keepEq); ++eqseen; }
            else               keep = false;
            o[c] = keep ? f * rscale : 0.0f;
        }
        __builtin_nontemporal_store(o, &orow[j * TPB + t]);
    }
}

extern "C" void kernel_launch(void* const* d_in, const int* in_sizes, int n_in,
                              void* d_out, int out_size, void* d_ws, size_t ws_size,
                              hipStream_t stream) {
    const float* feat  = (const float*)d_in[0];
    const float* prop  = (const float*)d_in[1];
    const float* scale = (const float*)d_in[2];
    float* out = (float*)d_out;
    const int batch = in_sizes[1];   // prop has one entry per row
    adaptive_drop_kernel<<<batch, TPB, 0, stream>>>(feat, prop, scale, out);
}

// Round 8
// 470.686 us; speedup vs baseline: 1.0116x; 1.0116x over previous
//
#include <hip/hip_runtime.h>

#define FEATSIZE 4096
#define TPB 256

typedef float f32x4 __attribute__((ext_vector_type(4)));

// One block per row. Radix-select (MSB-first, 8 bits x 4 passes) over
// order-preserving u32 keys held entirely in registers (16/thread).
// CRITICAL: every keys[] access is compile-time indexed (static unroll) --
// runtime indexing (e.g. e=ctz(mask)) demotes the array to scratch/local
// memory, doubling HBM traffic (round-2 evidence: VGPR_Count=32, dur ~2x
// memory floor). Candidate passes 2-4 use predicated static loops instead.
__global__ __launch_bounds__(TPB, 4) void adaptive_drop_kernel(
    const float* __restrict__ feat,
    const float* __restrict__ prop,
    const float* __restrict__ scale,
    float* __restrict__ out)
{
    __shared__ unsigned int hist[2][256];
    __shared__ unsigned int wtot[4];
    __shared__ unsigned int wsum[16];
    __shared__ unsigned int selB;
    __shared__ unsigned int selE;

    const int row  = blockIdx.x;
    const int t    = threadIdx.x;
    const int lane = t & 63;
    const int w    = t >> 6;

    const float p      = prop[row];
    const float rscale = scale[0] / p;
    int k = (int)rintf((float)FEATSIZE * p);   // matches jnp.round (half-to-even)
    k = k < 0 ? 0 : (k > FEATSIZE ? FEATSIZE : k);

    const f32x4* frow = reinterpret_cast<const f32x4*>(feat + (size_t)row * FEATSIZE);
    f32x4*       orow = reinterpret_cast<f32x4*>(out + (size_t)row * FEATSIZE);

    hist[0][t] = 0;
    hist[1][t] = 0;
    __syncthreads();

    // ---- loads issued together; pass-1 atomics per chunk hide under vmcnt ----
    f32x4 v0 = __builtin_nontemporal_load(&frow[0 * TPB + t]);
    f32x4 v1 = __builtin_nontemporal_load(&frow[1 * TPB + t]);
    f32x4 v2 = __builtin_nontemporal_load(&frow[2 * TPB + t]);
    f32x4 v3 = __builtin_nontemporal_load(&frow[3 * TPB + t]);

    unsigned int keys[16];
#define PROC_CHUNK(J, V)                                                        \
    do {                                                                        \
        _Pragma("unroll")                                                       \
        for (int c = 0; c < 4; ++c) {                                           \
            unsigned int u_ = __float_as_uint((V)[c]);                          \
            unsigned int key_ =                                                 \
                u_ ^ ((u_ & 0x80000000u) ? 0xFFFFFFFFu : 0x80000000u);          \
            keys[(J) * 4 + c] = key_;                                           \
            atomicAdd(&hist[0][key_ >> 24], 1u);                                \
        }                                                                       \
    } while (0)
    PROC_CHUNK(0, v0);
    PROC_CHUNK(1, v1);
    PROC_CHUNK(2, v2);
    PROC_CHUNK(3, v3);
#undef PROC_CHUNK

    // ---- trivial cases (block-uniform; not hit with setup's prop range) ----
    if (k <= 0 || k >= FEATSIZE) {
        const float m = (k >= FEATSIZE) ? rscale : 0.0f;
#pragma unroll
        for (int j = 0; j < 4; ++j) {
            f32x4 o;
#pragma unroll
            for (int c = 0; c < 4; ++c) {
                unsigned int key = keys[j * 4 + c];
                unsigned int u = (key & 0x80000000u) ? (key ^ 0x80000000u) : ~key;
                o[c] = __uint_as_float(u) * m;
            }
            __builtin_nontemporal_store(o, &orow[j * TPB + t]);
        }
        return;
    }

    // ---- radix select: find key T of rank k-1 (0-indexed ascending) ----
    int s = k - 1;
    unsigned int prefix = 0;
    unsigned int cand = 0;

    // pass 1 scan (histogram already built above)
    {
        __syncthreads();
        unsigned int val  = hist[0][t];
        unsigned int incl = val;
#pragma unroll
        for (int off = 1; off < 64; off <<= 1) {
            unsigned int o = __shfl_up(incl, (unsigned)off, 64);
            if (lane >= off) incl += o;
        }
        if (lane == 63) wtot[w] = incl;
        __syncthreads();
        unsigned int base = 0;
#pragma unroll
        for (int ww = 0; ww < 3; ++ww) if (ww < w) base += wtot[ww];
        const unsigned int cumIncl = base + incl;
        const unsigned int cumExcl = cumIncl - val;
        if (val != 0u && (int)cumExcl <= s && s < (int)cumIncl) {
            selB = (unsigned int)t;   // exactly one thread matches
            selE = cumExcl;
        }
        __syncthreads();
        const unsigned int b = selB;
        s -= (int)selE;
        prefix = b << 24;
#pragma unroll
        for (int e = 0; e < 16; ++e)
            if ((keys[e] >> 24) == b) cand |= (1u << e);
    }

    // passes 2..4: only candidate elements participate (~16 in whole block).
    // All keys[] indices are compile-time constants (predicated static loops).
#pragma unroll
    for (int pp = 1; pp < 4; ++pp) {
        const int shift = 24 - 8 * pp;
        unsigned int* H = hist[pp & 1];
#pragma unroll
        for (int e = 0; e < 16; ++e) {
            if (cand & (1u << e))
                atomicAdd(&H[(keys[e] >> shift) & 255u], 1u);
        }
        hist[(pp & 1) ^ 1][t] = 0;   // re-zero the buffer the NEXT pass will use
        __syncthreads();
        unsigned int val  = H[t];
        unsigned int incl = val;
#pragma unroll
        for (int off = 1; off < 64; off <<= 1) {
            unsigned int o = __shfl_up(incl, (unsigned)off, 64);
            if (lane >= off) incl += o;
        }
        if (lane == 63) wtot[w] = incl;
        __syncthreads();
        unsigned int base = 0;
#pragma unroll
        for (int ww = 0; ww < 3; ++ww) if (ww < w) base += wtot[ww];
        const unsigned int cumIncl = base + incl;
        const unsigned int cumExcl = cumIncl - val;
        if (val != 0u && (int)cumExcl <= s && s < (int)cumIncl) {
            selB = (unsigned int)t;
            selE = cumExcl;
        }
        __syncthreads();
        const unsigned int b = selB;
        s -= (int)selE;
        prefix |= b << shift;
        unsigned int nm = 0;
#pragma unroll
        for (int e = 0; e < 16; ++e) {
            if ((cand & (1u << e)) && ((keys[e] >> shift) & 255u) == b)
                nm |= (1u << e);
        }
        cand = nm;
    }

    const unsigned int T = prefix;
    const int keepEq = s + 1;   // # of elements equal to T to keep (lowest index first)

    // ---- stable rank among elements equal to T via ballot+popc ----
    const unsigned long long below = (1ULL << lane) - 1ULL;
    unsigned int laneExclJ[4];
#pragma unroll
    for (int j = 0; j < 4; ++j) {
        const unsigned long long m0 = __ballot(keys[j * 4 + 0] == T);
        const unsigned long long m1 = __ballot(keys[j * 4 + 1] == T);
        const unsigned long long m2 = __ballot(keys[j * 4 + 2] == T);
        const unsigned long long m3 = __ballot(keys[j * 4 + 3] == T);
        laneExclJ[j] = (unsigned int)(__popcll(m0 & below) + __popcll(m1 & below) +
                                      __popcll(m2 & below) + __popcll(m3 & below));
        if (lane == 0)
            wsum[j * 4 + w] = (unsigned int)(__popcll(m0) + __popcll(m1) +
                                             __popcll(m2) + __popcll(m3));
    }
    __syncthreads();
    unsigned int chunkExcl[4];
    {
        unsigned int run = 0;
#pragma unroll
        for (int m = 0; m < 16; ++m) {           // m = j*4 + w, global index order
            if ((m & 3) == w) chunkExcl[m >> 2] = run;
            run += wsum[m];
        }
    }

    // ---- masked, scaled write-out (coalesced float4, nontemporal) ----
#pragma unroll
    for (int j = 0; j < 4; ++j) {
        f32x4 o;
        const unsigned int base = chunkExcl[j] + laneExclJ[j];
        unsigned int eqseen = 0;
#pragma unroll
        for (int c = 0; c < 4; ++c) {
            const unsigned int key = keys[j * 4 + c];
            const unsigned int u = (key & 0x80000000u) ? (key ^ 0x80000000u) : ~key;
            const float f = __uint_as_float(u);
            bool keep;
            if (key < T)       keep = true;
            else if (key == T) { keep = ((int)(base + eqseen) < keepEq); ++eqseen; }
            else               keep = false;
            o[c] = keep ? f * rscale : 0.0f;
        }
        __builtin_nontemporal_store(o, &orow[j * TPB + t]);
    }
}

extern "C" void kernel_launch(void* const* d_in, const int* in_sizes, int n_in,
                              void* d_out, int out_size, void* d_ws, size_t ws_size,
                              hipStream_t stream) {
    const float* feat  = (const float*)d_in[0];
    const float* prop  = (const float*)d_in[1];
    const float* scale = (const float*)d_in[2];
    float* out = (float*)d_out;
    const int batch = in_sizes[1];   // prop has one entry per row
    adaptive_drop_kernel<<<batch, TPB, 0, stream>>>(feat, prop, scale, out);
}